// Round 1
// baseline (929.092 us; speedup 1.0000x reference)
//
#include <hip/hip_runtime.h>

// Problem constants (match reference)
constexpr int NB = 16384;   // B
constexpr int NK = 50;      // K
constexpr int NH = 64;      // H
constexpr float REG = 0.01f;

// acc[0] = sum (pred-target)^2   over B*K
// acc[1] = sum ||ue||            over B
// acc[2] = sum ||ie||            over B*K

__global__ __launch_bounds__(256) void mf_main(
    const float* __restrict__ user_weight,   // [NU, H]
    const float* __restrict__ item_weight,   // [NI, H]
    const float* __restrict__ user_bias,     // [NU, 1]
    const float* __restrict__ item_bias,     // [NI, 1]
    const float* __restrict__ gbias,         // [1]
    const float* __restrict__ target,        // [B, K]
    const int*   __restrict__ user,          // [B]
    const int*   __restrict__ item,          // [B, K]
    float* __restrict__ out,                 // [B*K + 1]
    float* __restrict__ acc)                 // [3] zeroed
{
    const int b    = blockIdx.x;
    const int tid  = threadIdx.x;
    const int wave = tid >> 6;
    const int lane = tid & 63;
    const int sub  = lane >> 4;   // 0..3 : which k within the wave's group
    const int l16  = lane & 15;   // 0..15: position within the H=64 row (float4 granules)

    // ---- user embedding: 16 lanes x float4 cover H=64; replicated across subgroups ----
    const int u = user[b];
    const float ubv = user_bias[u];
    const float4 uw4 = *reinterpret_cast<const float4*>(user_weight + (size_t)u * NH + l16 * 4);
    const float4 ue4 = make_float4(uw4.x + ubv, uw4.y + ubv, uw4.z + ubv, uw4.w + ubv);
    const float gb = gbias[0];

    float mse_acc = 0.f;   // nonzero only on lanes with l16==0
    float ien_acc = 0.f;

    // 4 waves x 4 subgroups = 16 k's per iteration
    for (int kbase = 0; kbase < NK; kbase += 16) {
        const int k = kbase + wave * 4 + sub;
        if (k < NK) {
            const int it = item[b * NK + k];
            const float ibv = item_bias[it];   // same addr across 16 lanes -> HW broadcast
            const float4 iw4 = *reinterpret_cast<const float4*>(item_weight + (size_t)it * NH + l16 * 4);
            const float4 ie4 = make_float4(iw4.x + ibv, iw4.y + ibv, iw4.z + ibv, iw4.w + ibv);

            float prod = ue4.x * ie4.x + ue4.y * ie4.y + ue4.z * ie4.z + ue4.w * ie4.w;
            float sq   = ie4.x * ie4.x + ie4.y * ie4.y + ie4.z * ie4.z + ie4.w * ie4.w;
            #pragma unroll
            for (int off = 8; off > 0; off >>= 1) {
                prod += __shfl_down(prod, off, 16);
                sq   += __shfl_down(sq,   off, 16);
            }
            if (l16 == 0) {
                const float pred = prod + gb;
                out[b * NK + k] = pred;
                const float d = pred - target[b * NK + k];
                mse_acc += d * d;
                ien_acc += sqrtf(sq);
            }
        }
    }

    // ---- ||ue|| : reduce lanes 0..15 of wave 0 ----
    float ue_norm = 0.f;
    if (wave == 0) {
        float s = ue4.x * ue4.x + ue4.y * ue4.y + ue4.z * ue4.z + ue4.w * ue4.w;
        #pragma unroll
        for (int off = 8; off > 0; off >>= 1) s += __shfl_down(s, off, 16);
        if (lane == 0) ue_norm = sqrtf(s);
    }

    // ---- block reduction: partials live on lanes {0,16,32,48} of each wave ----
    mse_acc += __shfl_down(mse_acc, 32);
    mse_acc += __shfl_down(mse_acc, 16);
    ien_acc += __shfl_down(ien_acc, 32);
    ien_acc += __shfl_down(ien_acc, 16);

    __shared__ float sm[4], si[4];
    if (lane == 0) { sm[wave] = mse_acc; si[wave] = ien_acc; }
    __syncthreads();
    if (tid == 0) {
        const float m = sm[0] + sm[1] + sm[2] + sm[3];
        const float i = si[0] + si[1] + si[2] + si[3];
        atomicAdd(&acc[0], m);        // device-scope by default (G12)
        atomicAdd(&acc[1], ue_norm);
        atomicAdd(&acc[2], i);
    }
}

__global__ void mf_finish(const float* __restrict__ acc, float* __restrict__ out)
{
    const float inv_bk = 1.0f / (float)(NB * NK);
    const float mse = acc[0] * inv_bk;
    const float loss = mse + REG * (acc[1] / (float)NB) + REG * (acc[2] * inv_bk);
    out[NB * NK] = loss;
}

extern "C" void kernel_launch(void* const* d_in, const int* in_sizes, int n_in,
                              void* d_out, int out_size, void* d_ws, size_t ws_size,
                              hipStream_t stream) {
    const float* user_weight = (const float*)d_in[0];
    const float* item_weight = (const float*)d_in[1];
    const float* user_bias   = (const float*)d_in[2];
    const float* item_bias   = (const float*)d_in[3];
    const float* gbias       = (const float*)d_in[4];
    const float* target      = (const float*)d_in[5];
    const int*   user        = (const int*)d_in[6];
    const int*   item        = (const int*)d_in[7];
    float* out = (float*)d_out;
    float* acc = (float*)d_ws;

    hipMemsetAsync(acc, 0, 3 * sizeof(float), stream);  // stream-ordered, capture-safe
    mf_main<<<NB, 256, 0, stream>>>(user_weight, item_weight, user_bias, item_bias,
                                    gbias, target, user, item, out, acc);
    mf_finish<<<1, 1, 0, stream>>>(acc, out);
}

// Round 2
// 461.499 us; speedup vs baseline: 2.0132x; 2.0132x over previous
//
#include <hip/hip_runtime.h>

// Problem constants (match reference)
constexpr int NB = 16384;   // B
constexpr int NK = 50;      // K
constexpr int NH = 64;      // H
constexpr float REG = 0.01f;

// acc[0] = sum (pred-target)^2 over B*K
// acc[1] = sum ||ue||          over B
// acc[2] = sum ||ie||          over B*K

// One block = 4 waves = 4 b's. One lane = one (b,k) pair; dot is fully in-lane.
__global__ __launch_bounds__(256) void mf_main(
    const float* __restrict__ user_weight,   // [NU, H]
    const float* __restrict__ item_weight,   // [NI, H]
    const float* __restrict__ user_bias,     // [NU, 1]
    const float* __restrict__ item_bias,     // [NI, 1]
    const float* __restrict__ gbias,         // [1]
    const float* __restrict__ target,        // [B, K]
    const int*   __restrict__ user,          // [B]
    const int*   __restrict__ item,          // [B, K]
    float* __restrict__ out,                 // [B*K + 1]
    float* __restrict__ acc)                 // [3] zeroed
{
    const int tid  = threadIdx.x;
    const int wave = tid >> 6;
    const int lane = tid & 63;
    const int b    = blockIdx.x * 4 + wave;

    __shared__ __align__(16) float s_ue[4][NH];
    __shared__ float s_red[3][4];

    // ---- user phase: 64 lanes cooperatively load the 64-float user row ----
    const int u = user[b];
    const float ubv = user_bias[u];
    const float uev = user_weight[(size_t)u * NH + lane] + ubv;
    s_ue[wave][lane] = uev;

    // ||ue||^2 wave reduction (each lane holds one element)
    float us = uev * uev;
    #pragma unroll
    for (int off = 32; off > 0; off >>= 1) us += __shfl_down(us, off);

    __syncthreads();   // make s_ue visible (also orders ds_write before ds_read)

    // ---- item phase: lane k handles one (b,k); 16 independent dwordx4 loads ----
    const float gb = gbias[0];
    float mse = 0.f, ien = 0.f;
    if (lane < NK) {
        const int idx = b * NK + lane;
        const int it  = item[idx];
        const float ibv = item_bias[it];
        const float tgt = target[idx];
        const float4* row = reinterpret_cast<const float4*>(item_weight + (size_t)it * NH);
        const float4* uep = reinterpret_cast<const float4*>(&s_ue[wave][0]);

        float4 r[16];
        #pragma unroll
        for (int i = 0; i < 16; ++i) r[i] = row[i];   // all 16 loads in flight

        float dot = 0.f, sq = 0.f;
        #pragma unroll
        for (int i = 0; i < 16; ++i) {
            const float4 ue4 = uep[i];                // same addr all lanes -> LDS broadcast
            const float iex = r[i].x + ibv;
            const float iey = r[i].y + ibv;
            const float iez = r[i].z + ibv;
            const float iew = r[i].w + ibv;
            dot += iex * ue4.x + iey * ue4.y + iez * ue4.z + iew * ue4.w;
            sq  += iex * iex   + iey * iey   + iez * iez   + iew * iew;
        }
        const float pred = dot + gb;
        out[idx] = pred;
        const float d = pred - tgt;
        mse = d * d;
        ien = sqrtf(sq);
    }

    // ---- wave reduce mse / ien (idle lanes contribute 0) ----
    #pragma unroll
    for (int off = 32; off > 0; off >>= 1) {
        mse += __shfl_down(mse, off);
        ien += __shfl_down(ien, off);
    }

    if (lane == 0) {
        s_red[0][wave] = mse;
        s_red[1][wave] = sqrtf(us);   // ||ue|| for this wave's b
        s_red[2][wave] = ien;
    }
    __syncthreads();
    if (tid == 0) {
        atomicAdd(&acc[0], s_red[0][0] + s_red[0][1] + s_red[0][2] + s_red[0][3]);
        atomicAdd(&acc[1], s_red[1][0] + s_red[1][1] + s_red[1][2] + s_red[1][3]);
        atomicAdd(&acc[2], s_red[2][0] + s_red[2][1] + s_red[2][2] + s_red[2][3]);
    }
}

__global__ void mf_finish(const float* __restrict__ acc, float* __restrict__ out)
{
    const float inv_bk = 1.0f / (float)(NB * NK);
    const float mse = acc[0] * inv_bk;
    const float loss = mse + REG * (acc[1] / (float)NB) + REG * (acc[2] * inv_bk);
    out[NB * NK] = loss;
}

extern "C" void kernel_launch(void* const* d_in, const int* in_sizes, int n_in,
                              void* d_out, int out_size, void* d_ws, size_t ws_size,
                              hipStream_t stream) {
    const float* user_weight = (const float*)d_in[0];
    const float* item_weight = (const float*)d_in[1];
    const float* user_bias   = (const float*)d_in[2];
    const float* item_bias   = (const float*)d_in[3];
    const float* gbias       = (const float*)d_in[4];
    const float* target      = (const float*)d_in[5];
    const int*   user        = (const int*)d_in[6];
    const int*   item        = (const int*)d_in[7];
    float* out = (float*)d_out;
    float* acc = (float*)d_ws;

    hipMemsetAsync(acc, 0, 3 * sizeof(float), stream);
    mf_main<<<NB / 4, 256, 0, stream>>>(user_weight, item_weight, user_bias, item_bias,
                                        gbias, target, user, item, out, acc);
    mf_finish<<<1, 1, 0, stream>>>(acc, out);
}

// Round 3
// 370.383 us; speedup vs baseline: 2.5085x; 1.2460x over previous
//
#include <hip/hip_runtime.h>

// Problem constants (match reference)
constexpr int NB = 16384;   // B
constexpr int NK = 50;      // K
constexpr int NH = 64;      // H
constexpr float REG = 0.01f;
constexpr int G  = 4;       // b's per wave

// acc[0] = sum (pred-target)^2 over B*K
// acc[1] = sum ||ue||          over B
// acc[2] = sum ||ie||          over B*K

// Block = 4 independent waves (no barrier in the hot loop).
// Wave handles G consecutive b's; lane = one (b,k) pair, dot fully in-lane.
__global__ __launch_bounds__(256) void mf_main(
    const float* __restrict__ user_weight,   // [NU, H]
    const float* __restrict__ item_weight,   // [NI, H]
    const float* __restrict__ user_bias,     // [NU, 1]
    const float* __restrict__ item_bias,     // [NI, 1]
    const float* __restrict__ gbias,         // [1]
    const float* __restrict__ target,        // [B, K]
    const int*   __restrict__ user,          // [B]
    const int*   __restrict__ item,          // [B, K]
    float* __restrict__ out,                 // [B*K + 1]
    float* __restrict__ acc)                 // [3] zeroed
{
    const int tid  = threadIdx.x;
    const int wave = tid >> 6;
    const int lane = tid & 63;
    const int kcl  = (lane < NK) ? lane : (NK - 1);  // clamped k (no exec branch)
    const bool active = (lane < NK);

    __shared__ __align__(16) float s_ue[4][NH];      // strictly per-wave slot
    __shared__ float s_red[3][4];

    const float gb = gbias[0];

    int b  = (blockIdx.x * 4 + wave) * G;
    // prologue: indices for g=0
    int u  = user[b];
    int it = item[b * NK + kcl];

    float mse_acc = 0.f, ien_acc = 0.f, uen_acc = 0.f;

    #pragma unroll
    for (int g = 0; g < G; ++g) {
        // ---- issue all gathers for current b ----
        const float ubv = user_bias[u];
        const float ibv = item_bias[it];
        const float tgt = target[b * NK + kcl];
        const float uev = user_weight[(size_t)u * NH + lane] + ubv;

        const float4* rowp = reinterpret_cast<const float4*>(item_weight + (size_t)it * NH);
        float4 r[16];
        #pragma unroll
        for (int i = 0; i < 16; ++i) r[i] = rowp[i];   // 16 independent dwordx4 in flight

        // ---- prefetch next b's indices while rows are in flight ----
        int nu = u, nit = it;
        if (g + 1 < G) {
            nu  = user[b + 1];
            nit = item[(b + 1) * NK + kcl];
        }

        // ---- user norm (wave-level, independent of item rows) ----
        s_ue[wave][lane] = uev;                        // own slot: lgkmcnt orders, no barrier
        float us = uev * uev;
        #pragma unroll
        for (int off = 32; off > 0; off >>= 1) us += __shfl_down(us, off);
        if (lane == 0) uen_acc += sqrtf(us);

        // ---- dot against LDS-broadcast ue ----
        const float4* uep = reinterpret_cast<const float4*>(&s_ue[wave][0]);
        float dot = 0.f, sq = 0.f;
        #pragma unroll
        for (int i = 0; i < 16; ++i) {
            const float4 ue4 = uep[i];                 // same addr all lanes -> broadcast
            const float iex = r[i].x + ibv;
            const float iey = r[i].y + ibv;
            const float iez = r[i].z + ibv;
            const float iew = r[i].w + ibv;
            dot += iex * ue4.x + iey * ue4.y + iez * ue4.z + iew * ue4.w;
            sq  += iex * iex   + iey * iey   + iez * iez   + iew * iew;
        }
        const float pred = dot + gb;
        if (active) {
            out[b * NK + lane] = pred;
            const float d = pred - tgt;
            mse_acc += d * d;
            ien_acc += sqrtf(sq);
        }

        b += 1; u = nu; it = nit;
    }

    // ---- one wave reduction at the end ----
    #pragma unroll
    for (int off = 32; off > 0; off >>= 1) {
        mse_acc += __shfl_down(mse_acc, off);
        ien_acc += __shfl_down(ien_acc, off);
    }
    if (lane == 0) {
        s_red[0][wave] = mse_acc;
        s_red[1][wave] = uen_acc;
        s_red[2][wave] = ien_acc;
    }
    __syncthreads();
    if (tid == 0) {
        atomicAdd(&acc[0], s_red[0][0] + s_red[0][1] + s_red[0][2] + s_red[0][3]);
        atomicAdd(&acc[1], s_red[1][0] + s_red[1][1] + s_red[1][2] + s_red[1][3]);
        atomicAdd(&acc[2], s_red[2][0] + s_red[2][1] + s_red[2][2] + s_red[2][3]);
    }
}

__global__ void mf_finish(const float* __restrict__ acc, float* __restrict__ out)
{
    const float inv_bk = 1.0f / (float)(NB * NK);
    const float mse = acc[0] * inv_bk;
    const float loss = mse + REG * (acc[1] / (float)NB) + REG * (acc[2] * inv_bk);
    out[NB * NK] = loss;
}

extern "C" void kernel_launch(void* const* d_in, const int* in_sizes, int n_in,
                              void* d_out, int out_size, void* d_ws, size_t ws_size,
                              hipStream_t stream) {
    const float* user_weight = (const float*)d_in[0];
    const float* item_weight = (const float*)d_in[1];
    const float* user_bias   = (const float*)d_in[2];
    const float* item_bias   = (const float*)d_in[3];
    const float* gbias       = (const float*)d_in[4];
    const float* target      = (const float*)d_in[5];
    const int*   user        = (const int*)d_in[6];
    const int*   item        = (const int*)d_in[7];
    float* out = (float*)d_out;
    float* acc = (float*)d_ws;

    hipMemsetAsync(acc, 0, 3 * sizeof(float), stream);
    mf_main<<<NB / (4 * G), 256, 0, stream>>>(user_weight, item_weight, user_bias, item_bias,
                                              gbias, target, user, item, out, acc);
    mf_finish<<<1, 1, 0, stream>>>(acc, out);
}